// Round 3
// baseline (278.846 us; speedup 1.0000x reference)
//
#include <hip/hip_runtime.h>
#include <hip/hip_bf16.h>

#define LN_EPS 1e-5f

// ---------------------------------------------------------------------------
// Kernel 1: embed + pos + row attention (seq over 64 bins) + residual + LN
// one block per (b, s): 256 blocks x 256 threads
// ---------------------------------------------------------------------------
__global__ __launch_bounds__(256) void k_row(
    const float* __restrict__ ctcf, const float* __restrict__ hac,
    const float* __restrict__ me1,  const float* __restrict__ me3,
    const float* __restrict__ ew,   const float* __restrict__ eb,
    const float* __restrict__ pe,
    const float* __restrict__ w_in, const float* __restrict__ b_in,
    const float* __restrict__ w_out,const float* __restrict__ b_out,
    const float* __restrict__ ln_g, const float* __restrict__ ln_b,
    float* __restrict__ msaR)
{
    __shared__ float sx[64][33];      // input tile (residual source)
    __shared__ float sqkv[64][100];   // qkv (96, padded); cols 0..31 reused for y
    __shared__ float so[64][33];      // attention output
    __shared__ float swin[96 * 32];
    __shared__ float swout[32 * 32];
    __shared__ float sbin[96];
    __shared__ float sbout[32], sg[32], sb[32];
    __shared__ float smean[64], srstd[64];

    const int blk = blockIdx.x;          // b*4 + s
    const int s   = blk & 3;
    const int b   = blk >> 2;
    const int tid = threadIdx.x;

    const float* chip = (s == 0) ? ctcf : (s == 1) ? hac : (s == 2) ? me1 : me3;

    // stage weights to LDS
    for (int n = tid; n < 96 * 32; n += 256) swin[n] = w_in[n];
    for (int n = tid; n < 32 * 32; n += 256) swout[n] = w_out[n];
    if (tid < 96) sbin[tid] = b_in[tid];
    if (tid < 32) {
        sbout[tid] = b_out[tid];
        sg[tid] = ln_g[tid];
        sb[tid] = ln_b[tid];
    }

    // x[l][c] = sig[l]*ew[c] + eb[c] + pe[l][c]
    for (int n = tid; n < 2048; n += 256) {
        int l = n >> 5, c = n & 31;
        float sig = chip[b * 64 + l];
        sx[l][c] = sig * ew[c] + eb[c] + pe[l * 32 + c];
    }
    __syncthreads();

    // qkv = x @ w_in^T + b_in : 64x96 outputs, 24 per thread
    for (int i = 0; i < 24; ++i) {
        int n = i * 256 + tid;           // 0..6143
        int l = n / 96;
        int cc = n - l * 96;
        float acc = sbin[cc];
        const float* wr = &swin[cc * 32];
        const float* xr = &sx[l][0];
#pragma unroll
        for (int c = 0; c < 32; ++c) acc += xr[c] * wr[c];
        sqkv[l][cc] = acc;
    }
    __syncthreads();

    // attention: one thread per (h, l); online softmax over j
    {
        const int h = tid >> 6;          // 0..3
        const int l = tid & 63;
        float q[8];
#pragma unroll
        for (int dd = 0; dd < 8; ++dd) q[dd] = sqkv[l][h * 8 + dd];
        const float scale = 0.35355339059327373f;  // 1/sqrt(8)
        float mrun = -1e30f, denom = 0.f, acc[8];
#pragma unroll
        for (int dd = 0; dd < 8; ++dd) acc[dd] = 0.f;
        for (int j = 0; j < 64; ++j) {
            float sc = 0.f;
#pragma unroll
            for (int dd = 0; dd < 8; ++dd) sc += q[dd] * sqkv[j][32 + h * 8 + dd];
            sc *= scale;
            float mnew = fmaxf(mrun, sc);
            float corr = __expf(mrun - mnew);
            float w = __expf(sc - mnew);
            denom = denom * corr + w;
#pragma unroll
            for (int dd = 0; dd < 8; ++dd)
                acc[dd] = acc[dd] * corr + w * sqkv[j][64 + h * 8 + dd];
            mrun = mnew;
        }
        float inv = 1.f / denom;
#pragma unroll
        for (int dd = 0; dd < 8; ++dd) so[l][h * 8 + dd] = acc[dd] * inv;
    }
    __syncthreads();

    // out proj + residual -> reuse sqkv[l][c] (cols 0..31, q no longer needed)
    for (int i = 0; i < 8; ++i) {
        int n = i * 256 + tid;
        int l = n >> 5, c = n & 31;
        float acc = sbout[c] + sx[l][c];
        const float* wr = &swout[c * 32];
#pragma unroll
        for (int k = 0; k < 32; ++k) acc += so[l][k] * wr[k];
        sqkv[l][c] = acc;
    }
    __syncthreads();

    // LN stats per token
    if (tid < 64) {
        float mu = 0.f;
#pragma unroll
        for (int c = 0; c < 32; ++c) mu += sqkv[tid][c];
        mu *= (1.f / 32.f);
        float var = 0.f;
#pragma unroll
        for (int c = 0; c < 32; ++c) { float d = sqkv[tid][c] - mu; var += d * d; }
        var *= (1.f / 32.f);
        smean[tid] = mu;
        srstd[tid] = rsqrtf(var + LN_EPS);
    }
    __syncthreads();

    float* outp = msaR + blk * 2048;     // layout (B,S,Lb,C)
    for (int n = tid; n < 2048; n += 256) {
        int l = n >> 5, c = n & 31;
        outp[n] = (sqkv[l][c] - smean[l]) * srstd[l] * sg[c] + sb[c];
    }
}

// ---------------------------------------------------------------------------
// Kernel 2: column attention (seq over 4 tracks) + residual + LN + track mean
// one block per (b, l): 4096 blocks x 64 threads
// ---------------------------------------------------------------------------
__global__ __launch_bounds__(64) void k_col(
    const float* __restrict__ msaR,
    const float* __restrict__ w_in, const float* __restrict__ b_in,
    const float* __restrict__ w_out,const float* __restrict__ b_out,
    const float* __restrict__ ln_g, const float* __restrict__ ln_b,
    float* __restrict__ m_out, float* __restrict__ nrm_out)
{
    __shared__ float sx[4][33];
    __shared__ float sqkv[4][100];
    __shared__ float so[4][33];
    __shared__ float sy[4][33];
    __shared__ float mean4[4], rstd4[4];
    __shared__ float smv[32];

    const int blk = blockIdx.x;      // b*64 + l
    const int b = blk >> 6, l = blk & 63;
    const int tid = threadIdx.x;

    // x[s][c] = msaR[b, s, l, c]
    for (int n = tid; n < 128; n += 64) {
        int s = n >> 5, c = n & 31;
        sx[s][c] = msaR[((b * 4 + s) * 64 + l) * 32 + c];
    }
    __syncthreads();

    // qkv: 4x96 outputs, 6 per thread
    for (int i = 0; i < 6; ++i) {
        int n = i * 64 + tid;
        int s = n / 96;
        int cc = n - s * 96;
        float acc = b_in[cc];
        const float* wr = &w_in[cc * 32];
#pragma unroll
        for (int c = 0; c < 32; ++c) acc += sx[s][c] * wr[c];
        sqkv[s][cc] = acc;
    }
    __syncthreads();

    // attention: threads 0..15 = (h, i)
    if (tid < 16) {
        const int h = tid >> 2, i = tid & 3;
        const float scale = 0.35355339059327373f;
        float q[8];
#pragma unroll
        for (int dd = 0; dd < 8; ++dd) q[dd] = sqkv[i][h * 8 + dd];
        float sc[4];
        float mx = -1e30f;
#pragma unroll
        for (int j = 0; j < 4; ++j) {
            float v = 0.f;
#pragma unroll
            for (int dd = 0; dd < 8; ++dd) v += q[dd] * sqkv[j][32 + h * 8 + dd];
            sc[j] = v * scale;
            mx = fmaxf(mx, sc[j]);
        }
        float den = 0.f;
#pragma unroll
        for (int j = 0; j < 4; ++j) { sc[j] = __expf(sc[j] - mx); den += sc[j]; }
        float inv = 1.f / den;
#pragma unroll
        for (int dd = 0; dd < 8; ++dd) {
            float a = 0.f;
#pragma unroll
            for (int j = 0; j < 4; ++j) a += sc[j] * sqkv[j][64 + h * 8 + dd];
            so[i][h * 8 + dd] = a * inv;
        }
    }
    __syncthreads();

    // out proj + residual
    for (int n = tid; n < 128; n += 64) {
        int s = n >> 5, c = n & 31;
        float acc = b_out[c] + sx[s][c];
        const float* wr = &w_out[c * 32];
#pragma unroll
        for (int k = 0; k < 32; ++k) acc += so[s][k] * wr[k];
        sy[s][c] = acc;
    }
    __syncthreads();

    if (tid < 4) {
        float mu = 0.f;
#pragma unroll
        for (int c = 0; c < 32; ++c) mu += sy[tid][c];
        mu *= (1.f / 32.f);
        float var = 0.f;
#pragma unroll
        for (int c = 0; c < 32; ++c) { float d = sy[tid][c] - mu; var += d * d; }
        var *= (1.f / 32.f);
        mean4[tid] = mu;
        rstd4[tid] = rsqrtf(var + LN_EPS);
    }
    __syncthreads();

    // track mean of LN output; mean over s of (norm*g + b) = g*mean(norm) + b
    if (tid < 32) {
        int c = tid;
        float acc = 0.f;
#pragma unroll
        for (int s = 0; s < 4; ++s) acc += (sy[s][c] - mean4[s]) * rstd4[s];
        float mval = 0.25f * acc * ln_g[c] + ln_b[c];
        m_out[blk * 32 + c] = mval;
        smv[c] = mval * mval;
    }
    __syncthreads();

    if (tid == 0) {
        float sum = 0.f;
#pragma unroll
        for (int c = 0; c < 32; ++c) sum += smv[c];
        nrm_out[blk] = sqrtf(sum);
    }
}

// ---------------------------------------------------------------------------
// Kernel 3: factorized outer-product + proj + LN + SiLU + transpose
// pair/nrm = (m_i ⊗ m_j)/(|m_i||m_j|); feat = T_i · m_j * inv + pb
// one block per (b, i): 4096 blocks x 64 threads (one thread per j)
// ---------------------------------------------------------------------------
__global__ __launch_bounds__(64) void k_pair(
    const float* __restrict__ m, const float* __restrict__ nrm,
    const float* __restrict__ pw, const float* __restrict__ pb,
    const float* __restrict__ pg, const float* __restrict__ pbeta,
    float* __restrict__ out)
{
    __shared__ float smj[64][33];
    __shared__ float sT[16][33];
    __shared__ float smi[32];
    __shared__ float snj[64];
    __shared__ float sbias[16], sgam[16], sbet[16];

    const int blk = blockIdx.x;   // b*64 + i
    const int b = blk >> 6, i = blk & 63;
    const int tid = threadIdx.x;

    const float* mb = m + b * 2048;
    for (int n = tid; n < 2048; n += 64) smj[n >> 5][n & 31] = mb[n];
    if (tid < 32) smi[tid] = mb[i * 32 + tid];
    if (tid < 16) {
        sbias[tid] = pb[tid];
        sgam[tid]  = pg[tid];
        sbet[tid]  = pbeta[tid];
    }
    snj[tid] = nrm[b * 64 + tid];
    __syncthreads();

    // T[cp][d] = sum_c pw[cp, c*32 + d] * m_i[c]  (512 outputs, 8/thread)
    for (int k = 0; k < 8; ++k) {
        int n = k * 64 + tid;
        int cp = n >> 5, d = n & 31;
        float acc = 0.f;
        const float* wr = &pw[cp * 1024 + d];
#pragma unroll
        for (int c = 0; c < 32; ++c) acc += wr[c * 32] * smi[c];
        sT[cp][d] = acc;
    }
    __syncthreads();

    const int j = tid;
    const float invn = 1.f / fmaxf(snj[i] * snj[j], 1e-6f);
    float f[16];
#pragma unroll
    for (int cp = 0; cp < 16; ++cp) {
        float acc = 0.f;
#pragma unroll
        for (int d = 0; d < 32; ++d) acc += sT[cp][d] * smj[j][d];
        f[cp] = acc * invn + sbias[cp];
    }
    // LN over CP=16, then SiLU
    float mu = 0.f;
#pragma unroll
    for (int cp = 0; cp < 16; ++cp) mu += f[cp];
    mu *= (1.f / 16.f);
    float var = 0.f;
#pragma unroll
    for (int cp = 0; cp < 16; ++cp) { float d = f[cp] - mu; var += d * d; }
    var *= (1.f / 16.f);
    const float rstd = rsqrtf(var + LN_EPS);
#pragma unroll
    for (int cp = 0; cp < 16; ++cp) {
        float v = (f[cp] - mu) * rstd * sgam[cp] + sbet[cp];
        float sl = v / (1.f + __expf(-v));
        out[((b * 16 + cp) * 64 + i) * 64 + j] = sl;
    }
}

// ---------------------------------------------------------------------------
extern "C" void kernel_launch(void* const* d_in, const int* in_sizes, int n_in,
                              void* d_out, int out_size, void* d_ws, size_t ws_size,
                              hipStream_t stream) {
    const float* ctcf  = (const float*)d_in[0];
    const float* hac   = (const float*)d_in[1];
    const float* me1   = (const float*)d_in[2];
    const float* me3   = (const float*)d_in[3];
    const float* ew    = (const float*)d_in[4];
    const float* ebias = (const float*)d_in[5];
    const float* pe    = (const float*)d_in[6];
    const float* riw   = (const float*)d_in[7];
    const float* rib   = (const float*)d_in[8];
    const float* row_  = (const float*)d_in[9];
    const float* rob   = (const float*)d_in[10];
    const float* rlg   = (const float*)d_in[11];
    const float* rlb   = (const float*)d_in[12];
    const float* ciw   = (const float*)d_in[13];
    const float* cib   = (const float*)d_in[14];
    const float* cow   = (const float*)d_in[15];
    const float* cob   = (const float*)d_in[16];
    const float* clg   = (const float*)d_in[17];
    const float* clb   = (const float*)d_in[18];
    const float* pw    = (const float*)d_in[19];
    const float* pb    = (const float*)d_in[20];
    const float* pg    = (const float*)d_in[21];
    const float* pbt   = (const float*)d_in[22];

    float* out = (float*)d_out;   // reference output dtype is float32

    // fp32 scratch: msaR (2 MB) borrows the out buffer (16 MB f32) — fully
    // read by k_col before k_pair overwrites out (same stream, serial).
    // m + norms live in ws (~528 KB).
    float* msaR = (float*)d_out;                 // 64*4*64*32 floats = 2 MB
    float* mbuf = (float*)d_ws;                  // 64*64*32 floats = 512 KB
    float* nbuf = mbuf + 64 * 64 * 32;           // 64*64 floats

    k_row<<<256, 256, 0, stream>>>(ctcf, hac, me1, me3, ew, ebias, pe,
                                   riw, rib, row_, rob, rlg, rlb, msaR);
    k_col<<<4096, 64, 0, stream>>>(msaR, ciw, cib, cow, cob, clg, clb,
                                   mbuf, nbuf);
    k_pair<<<4096, 64, 0, stream>>>(mbuf, nbuf, pw, pb, pg, pbt, out);
}

// Round 4
// 167.205 us; speedup vs baseline: 1.6677x; 1.6677x over previous
//
#include <hip/hip_runtime.h>
#include <hip/hip_bf16.h>

#define LN_EPS 1e-5f

// ---------------------------------------------------------------------------
// Kernel 1: embed + pos + row attention (64 bins) + residual + LN
// one block per (b, s): 256 blocks x 256 threads
// GEMM lane map: weight row is wave-uniform (broadcast), x row hoisted to regs.
// ---------------------------------------------------------------------------
__global__ __launch_bounds__(256) void k_row(
    const float* __restrict__ ctcf, const float* __restrict__ hac,
    const float* __restrict__ me1,  const float* __restrict__ me3,
    const float* __restrict__ ew,   const float* __restrict__ eb,
    const float* __restrict__ pe,
    const float* __restrict__ w_in, const float* __restrict__ b_in,
    const float* __restrict__ w_out,const float* __restrict__ b_out,
    const float* __restrict__ ln_g, const float* __restrict__ ln_b,
    float* __restrict__ msaR)
{
    __shared__ float sx[64][33];        // x tile (residual source)
    __shared__ float sqkv[64 * 100];    // qkv rows, stride 100 (16B-aligned)
    __shared__ float so[64][33];        // attention output
    __shared__ float swin[96 * 32];     // read broadcast -> no pad needed
    __shared__ float swout[32 * 32];
    __shared__ float sbin[96];
    __shared__ float sbout[32], sg[32], sb[32];
    __shared__ float smean[64], srstd[64];

    const int blk = blockIdx.x;          // b*4 + s
    const int s   = blk & 3;
    const int b   = blk >> 2;
    const int tid = threadIdx.x;

    const float* chip = (s == 0) ? ctcf : (s == 1) ? hac : (s == 2) ? me1 : me3;

    for (int n = tid; n < 96 * 32; n += 256) swin[n] = w_in[n];
    for (int n = tid; n < 32 * 32; n += 256) swout[n] = w_out[n];
    if (tid < 96) sbin[tid] = b_in[tid];
    if (tid < 32) {
        sbout[tid] = b_out[tid];
        sg[tid] = ln_g[tid];
        sb[tid] = ln_b[tid];
    }
    for (int n = tid; n < 2048; n += 256) {
        int l = n >> 5, c = n & 31;
        sx[l][c] = chip[b * 64 + l] * ew[c] + eb[c] + pe[l * 32 + c];
    }
    __syncthreads();

    const int l  = tid & 63;
    const int cg = tid >> 6;             // 0..3

    float xr[32];
#pragma unroll
    for (int c = 0; c < 32; ++c) xr[c] = sx[l][c];

    // qkv[l][cc] = x[l]·w_in[cc] + b_in[cc]; lanes share cc -> broadcast w read
#pragma unroll
    for (int i = 0; i < 24; ++i) {
        int cc = i * 4 + cg;
        const float* wr = &swin[cc * 32];
        float acc = sbin[cc];
#pragma unroll
        for (int c = 0; c < 32; ++c) acc += xr[c] * wr[c];
        sqkv[l * 100 + cc] = acc;
    }
    __syncthreads();

    // attention: thread (h = cg, l); online softmax over j (k/v reads broadcast)
    {
        const int h = cg;
        float q[8];
#pragma unroll
        for (int dd = 0; dd < 8; ++dd) q[dd] = sqkv[l * 100 + h * 8 + dd];
        const float scale = 0.35355339059327373f;  // 1/sqrt(8)
        float mrun = -1e30f, denom = 0.f, acc[8];
#pragma unroll
        for (int dd = 0; dd < 8; ++dd) acc[dd] = 0.f;
        for (int j = 0; j < 64; ++j) {
            const float* kr = &sqkv[j * 100 + 32 + h * 8];
            const float* vr = &sqkv[j * 100 + 64 + h * 8];
            float sc = 0.f;
#pragma unroll
            for (int dd = 0; dd < 8; ++dd) sc += q[dd] * kr[dd];
            sc *= scale;
            float mnew = fmaxf(mrun, sc);
            float corr = __expf(mrun - mnew);
            float w = __expf(sc - mnew);
            denom = denom * corr + w;
#pragma unroll
            for (int dd = 0; dd < 8; ++dd)
                acc[dd] = acc[dd] * corr + w * vr[dd];
            mrun = mnew;
        }
        float inv = 1.f / denom;
#pragma unroll
        for (int dd = 0; dd < 8; ++dd) so[l][h * 8 + dd] = acc[dd] * inv;
    }
    __syncthreads();

    // out proj + residual (xr regs) -> write into sqkv cols 0..31
    {
        float orow[32];
#pragma unroll
        for (int k = 0; k < 32; ++k) orow[k] = so[l][k];
#pragma unroll
        for (int i = 0; i < 8; ++i) {
            int c = i * 4 + cg;
            const float* wr = &swout[c * 32];
            float acc = sbout[c] + xr[c];
#pragma unroll
            for (int k = 0; k < 32; ++k) acc += orow[k] * wr[k];
            sqkv[l * 100 + c] = acc;
        }
    }
    __syncthreads();

    if (tid < 64) {
        float mu = 0.f;
#pragma unroll
        for (int c = 0; c < 32; ++c) mu += sqkv[tid * 100 + c];
        mu *= (1.f / 32.f);
        float var = 0.f;
#pragma unroll
        for (int c = 0; c < 32; ++c) { float d = sqkv[tid * 100 + c] - mu; var += d * d; }
        var *= (1.f / 32.f);
        smean[tid] = mu;
        srstd[tid] = rsqrtf(var + LN_EPS);
    }
    __syncthreads();

    float* outp = msaR + blk * 2048;     // (B,S,Lb,C)
    for (int n = tid; n < 2048; n += 256) {
        int ll = n >> 5, c = n & 31;
        outp[n] = (sqkv[ll * 100 + c] - smean[ll]) * srstd[ll] * sg[c] + sb[c];
    }
}

// ---------------------------------------------------------------------------
// Kernel 2: column attention (4 tracks) + residual + LN + track mean + norm
// one block per (b, 16-bin chunk): 256 blocks x 256 threads
// ---------------------------------------------------------------------------
__global__ __launch_bounds__(256) void k_col(
    const float* __restrict__ msaR,
    const float* __restrict__ w_in, const float* __restrict__ b_in,
    const float* __restrict__ w_out,const float* __restrict__ b_out,
    const float* __restrict__ ln_g, const float* __restrict__ ln_b,
    float* __restrict__ m_out, float* __restrict__ nrm_out)
{
    __shared__ float sx[64][33];        // rows keyed s*16+lo
    __shared__ float sqkv[64 * 100];    // rows keyed r = lo*4+s
    __shared__ float so[64][33];        // rows keyed r = l*4+i
    __shared__ float swi[96 * 32];
    __shared__ float swo[32 * 32];
    __shared__ float sbi[96];
    __shared__ float sbo[32], sg[32], sb[32];
    __shared__ float smean2[64], srstd2[64];
    __shared__ float smv[16][33];

    const int bx = blockIdx.x;           // 64 b x 4 chunks
    const int b  = bx >> 2;
    const int l0 = (bx & 3) * 16;
    const int tid = threadIdx.x;

    for (int n = tid; n < 96 * 32; n += 256) swi[n] = w_in[n];
    for (int n = tid; n < 32 * 32; n += 256) swo[n] = w_out[n];
    if (tid < 96) sbi[tid] = b_in[tid];
    if (tid < 32) {
        sbo[tid] = b_out[tid];
        sg[tid] = ln_g[tid];
        sb[tid] = ln_b[tid];
    }
    // x[s][lo][c] = msaR[b, s, l0+lo, c]
    for (int n = tid; n < 2048; n += 256) {
        int s = n >> 9, lo = (n >> 5) & 15, c = n & 31;
        sx[s * 16 + lo][c] = msaR[((b * 4 + s) * 64 + l0 + lo) * 32 + c];
    }
    __syncthreads();

    // thread -> token r = tid&63 with (s = r&3, lo = r>>2); cg = tid>>6
    const int r  = tid & 63;
    const int sS = r & 3, lo = r >> 2;
    const int cg = tid >> 6;

    float xr[32];
#pragma unroll
    for (int c = 0; c < 32; ++c) xr[c] = sx[sS * 16 + lo][c];

#pragma unroll
    for (int i = 0; i < 24; ++i) {
        int cc = i * 4 + cg;
        const float* wr = &swi[cc * 32];
        float acc = sbi[cc];
#pragma unroll
        for (int c = 0; c < 32; ++c) acc += xr[c] * wr[c];
        sqkv[r * 100 + cc] = acc;
    }
    __syncthreads();

    // attention: thread (la = tid>>4, h = (tid>>2)&3, ia = tid&3)
    {
        const int la = tid >> 4, h = (tid >> 2) & 3, ia = tid & 3;
        const float scale = 0.35355339059327373f;
        float q[8];
#pragma unroll
        for (int dd = 0; dd < 8; ++dd) q[dd] = sqkv[(la * 4 + ia) * 100 + h * 8 + dd];
        float sc[4];
        float mx = -1e30f;
#pragma unroll
        for (int jj = 0; jj < 4; ++jj) {
            const float* kr = &sqkv[(la * 4 + jj) * 100 + 32 + h * 8];
            float v = 0.f;
#pragma unroll
            for (int dd = 0; dd < 8; ++dd) v += q[dd] * kr[dd];
            sc[jj] = v * scale;
            mx = fmaxf(mx, sc[jj]);
        }
        float den = 0.f;
#pragma unroll
        for (int jj = 0; jj < 4; ++jj) { sc[jj] = __expf(sc[jj] - mx); den += sc[jj]; }
        float inv = 1.f / den;
#pragma unroll
        for (int dd = 0; dd < 8; ++dd) {
            float a = 0.f;
#pragma unroll
            for (int jj = 0; jj < 4; ++jj)
                a += sc[jj] * sqkv[(la * 4 + jj) * 100 + 64 + h * 8 + dd];
            so[la * 4 + ia][h * 8 + dd] = a * inv;
        }
    }
    __syncthreads();

    // out proj + residual -> sqkv cols 0..31
    {
        float orow[32];
#pragma unroll
        for (int k = 0; k < 32; ++k) orow[k] = so[r][k];
#pragma unroll
        for (int i = 0; i < 8; ++i) {
            int c = i * 4 + cg;
            const float* wr = &swo[c * 32];
            float acc = sbo[c] + xr[c];
#pragma unroll
            for (int k = 0; k < 32; ++k) acc += orow[k] * wr[k];
            sqkv[r * 100 + c] = acc;
        }
    }
    __syncthreads();

    if (tid < 64) {
        float mu = 0.f;
#pragma unroll
        for (int c = 0; c < 32; ++c) mu += sqkv[tid * 100 + c];
        mu *= (1.f / 32.f);
        float var = 0.f;
#pragma unroll
        for (int c = 0; c < 32; ++c) { float d = sqkv[tid * 100 + c] - mu; var += d * d; }
        var *= (1.f / 32.f);
        smean2[tid] = mu;
        srstd2[tid] = rsqrtf(var + LN_EPS);
    }
    __syncthreads();

    // track mean (over s) of LN output; write m and m^2 for the norm
    for (int pass = 0; pass < 2; ++pass) {
        int idx = pass * 256 + tid;      // 512 = 16 lo x 32 c
        int loo = idx >> 5, c = idx & 31;
        float acc = 0.f;
#pragma unroll
        for (int ss = 0; ss < 4; ++ss) {
            int rr = loo * 4 + ss;
            acc += (sqkv[rr * 100 + c] - smean2[rr]) * srstd2[rr];
        }
        float mval = 0.25f * acc * sg[c] + sb[c];
        m_out[(b * 64 + l0 + loo) * 32 + c] = mval;
        smv[loo][c] = mval * mval;
    }
    __syncthreads();

    if (tid < 16) {
        float sum = 0.f;
#pragma unroll
        for (int c = 0; c < 32; ++c) sum += smv[tid][c];
        nrm_out[b * 64 + l0 + tid] = sqrtf(sum);
    }
}

// ---------------------------------------------------------------------------
// Kernel 3: factorized outer-product + proj + LN + SiLU + transpose
// feat[b,i,j,cp] = (T_i[cp]·m_j)/(|m_i||m_j|) + pb;  T_i = pw·m_i
// one block per (b, 16-i chunk): 256 blocks x 256 threads
// pw staged ONCE per block into LDS, transposed to [cp*32+d][c] (pad 36)
// ---------------------------------------------------------------------------
__global__ __launch_bounds__(256) void k_pair(
    const float* __restrict__ m, const float* __restrict__ nrm,
    const float* __restrict__ pw, const float* __restrict__ pb,
    const float* __restrict__ pg, const float* __restrict__ pbeta,
    float* __restrict__ out)
{
    __shared__ float spw[512 * 36];     // [cp*32+d][c], pad 36 (16B-aligned rows)
    __shared__ float sT[16 * 520];      // [il][cp*32+d], stride 520 (aligned)
    __shared__ float smj[64][33];
    __shared__ float snj[64];
    __shared__ float sbias[16], sgam[16], sbet[16];

    const int bx = blockIdx.x;          // 64 b x 4 i-chunks
    const int b  = bx >> 2;
    const int i0 = (bx & 3) * 16;
    const int tid = threadIdx.x;

    const float* mb = m + b * 2048;
    for (int n = tid; n < 2048; n += 256) smj[n >> 5][n & 31] = mb[n];
    if (tid < 64) snj[tid] = nrm[b * 64 + tid];
    if (tid < 16) {
        sbias[tid] = pb[tid];
        sgam[tid]  = pg[tid];
        sbet[tid]  = pbeta[tid];
    }
    // transpose-stage pw: global coalesced, LDS writes conflict-light
    for (int n = tid; n < 16384; n += 256) {
        int cp = n >> 10, c = (n >> 5) & 31, d = n & 31;
        spw[(cp * 32 + d) * 36 + c] = pw[n];
    }
    __syncthreads();

    // T phase: thread (il = tid>>4, t16 = tid&15); 32 dots each
    {
        const int il = tid >> 4, t16 = tid & 15;
        const int ig = i0 + il;
        float mi[32];
#pragma unroll
        for (int c = 0; c < 32; ++c) mi[c] = smj[ig][c];
#pragma unroll
        for (int p = 0; p < 32; ++p) {
            int rem = p * 16 + t16;     // cp*32 + d
            const float* wr = &spw[rem * 36];
            float acc = 0.f;
#pragma unroll
            for (int c = 0; c < 32; ++c) acc += wr[c] * mi[c];
            sT[il * 520 + rem] = acc;
        }
    }
    __syncthreads();

    // out phase: thread (ih = tid>>6, j = tid&63); 4 i's per thread
    const int j  = tid & 63;
    const int ih = tid >> 6;
    float mj[32];
#pragma unroll
    for (int d = 0; d < 32; ++d) mj[d] = smj[j][d];
    const float nj = snj[j];

    for (int q = 0; q < 4; ++q) {
        const int il = ih * 4 + q;
        const int ig = i0 + il;
        const float invn = 1.f / fmaxf(snj[ig] * nj, 1e-6f);
        float f[16];
#pragma unroll
        for (int cp = 0; cp < 16; ++cp) {
            const float* tr = &sT[il * 520 + cp * 32];  // broadcast b128 reads
            float acc = 0.f;
#pragma unroll
            for (int d = 0; d < 32; ++d) acc += tr[d] * mj[d];
            f[cp] = acc * invn + sbias[cp];
        }
        float mu = 0.f;
#pragma unroll
        for (int cp = 0; cp < 16; ++cp) mu += f[cp];
        mu *= (1.f / 16.f);
        float var = 0.f;
#pragma unroll
        for (int cp = 0; cp < 16; ++cp) { float d = f[cp] - mu; var += d * d; }
        var *= (1.f / 16.f);
        const float rstd = rsqrtf(var + LN_EPS);
#pragma unroll
        for (int cp = 0; cp < 16; ++cp) {
            float v = (f[cp] - mu) * rstd * sgam[cp] + sbet[cp];
            float sl = v / (1.f + __expf(-v));
            out[((b * 16 + cp) * 64 + ig) * 64 + j] = sl;
        }
    }
}

// ---------------------------------------------------------------------------
extern "C" void kernel_launch(void* const* d_in, const int* in_sizes, int n_in,
                              void* d_out, int out_size, void* d_ws, size_t ws_size,
                              hipStream_t stream) {
    const float* ctcf  = (const float*)d_in[0];
    const float* hac   = (const float*)d_in[1];
    const float* me1   = (const float*)d_in[2];
    const float* me3   = (const float*)d_in[3];
    const float* ew    = (const float*)d_in[4];
    const float* ebias = (const float*)d_in[5];
    const float* pe    = (const float*)d_in[6];
    const float* riw   = (const float*)d_in[7];
    const float* rib   = (const float*)d_in[8];
    const float* row_  = (const float*)d_in[9];
    const float* rob   = (const float*)d_in[10];
    const float* rlg   = (const float*)d_in[11];
    const float* rlb   = (const float*)d_in[12];
    const float* ciw   = (const float*)d_in[13];
    const float* cib   = (const float*)d_in[14];
    const float* cow   = (const float*)d_in[15];
    const float* cob   = (const float*)d_in[16];
    const float* clg   = (const float*)d_in[17];
    const float* clb   = (const float*)d_in[18];
    const float* pw    = (const float*)d_in[19];
    const float* pb    = (const float*)d_in[20];
    const float* pg    = (const float*)d_in[21];
    const float* pbt   = (const float*)d_in[22];

    float* out = (float*)d_out;

    // msaR (2 MB) borrows d_out (16 MB f32): fully consumed by k_col before
    // k_pair writes out (serial stream). m + norms in ws (~528 KB).
    float* msaR = (float*)d_out;
    float* mbuf = (float*)d_ws;                  // 64*64*32 floats
    float* nbuf = mbuf + 64 * 64 * 32;           // 64*64 floats

    k_row<<<256, 256, 0, stream>>>(ctcf, hac, me1, me3, ew, ebias, pe,
                                   riw, rib, row_, rob, rlg, rlb, msaR);
    k_col<<<256, 256, 0, stream>>>(msaR, ciw, cib, cow, cob, clg, clb,
                                   mbuf, nbuf);
    k_pair<<<256, 256, 0, stream>>>(mbuf, nbuf, pw, pb, pg, pbt, out);
}